// Round 1
// baseline (2344.814 us; speedup 1.0000x reference)
//
#include <hip/hip_runtime.h>
#include <math.h>

#define NTHREADS 512

static __device__ __forceinline__ float gelu_f(float x) {
    return 0.5f * x * (1.0f + erff(x * 0.70710678118654752f));
}

// One block = one batch element. All state in LDS.
// xs/ys stride 65 (conflict-free for both token-parallel and channel-parallel access).
// qkv stride 196 floats (rows 16B-aligned for float4 loads).
template<int N, int P, int L, bool LAST>
__device__ __forceinline__ void layer_fn(
    float* __restrict__ xs, float* __restrict__ ys,
    float* __restrict__ qkv, float* __restrict__ wst, float* __restrict__ hbuf,
    const float* __restrict__ w_qkv, const float* __restrict__ b_qkv,
    const float* __restrict__ w_o,   const float* __restrict__ b_o,
    const float* __restrict__ ln1_g, const float* __restrict__ ln1_b,
    const float* __restrict__ ln2_g, const float* __restrict__ ln2_b,
    const float* __restrict__ w1,    const float* __restrict__ b1,
    const float* __restrict__ w2,    const float* __restrict__ b2,
    float* __restrict__ out, int b, int t)
{
    constexpr int XS = 65;
    constexpr int QS = 196;

    // ---- stage w_qkv (12288 floats) + LN1 (token per thread), one barrier ----
    for (int idx = t; idx < 64 * 192; idx += NTHREADS)
        wst[idx] = w_qkv[L * 64 * 192 + idx];
    if (t < N) {
        float s1 = 0.f, s2 = 0.f;
        #pragma unroll
        for (int d = 0; d < 64; ++d) {
            float v = xs[t * XS + d];
            s1 += v; s2 += v * v;
        }
        float m = s1 * 0.015625f;
        float var = s2 * 0.015625f - m * m;
        float r = rsqrtf(var + 1e-5f);
        #pragma unroll
        for (int d = 0; d < 64; ++d) {
            float v = xs[t * XS + d];
            ys[t * XS + d] = (v - m) * r * ln1_g[L * 64 + d] + ln1_b[L * 64 + d];
        }
    }
    __syncthreads();

    // ---- qkv GEMM: out[N][192] = ys @ wst + b_qkv. Register tile MI=8 x NO=4 ----
    {
        constexpr int NTI = (N + 7) / 8;
        for (int tile = t; tile < NTI * 48; tile += NTHREADS) {
            int i0 = (tile / 48) * 8;
            int o0 = (tile % 48) * 4;
            float4 bq = *(const float4*)&b_qkv[L * 192 + o0];
            float acc[8][4];
            #pragma unroll
            for (int r = 0; r < 8; ++r) {
                acc[r][0] = bq.x; acc[r][1] = bq.y; acc[r][2] = bq.z; acc[r][3] = bq.w;
            }
            int ir[8];
            #pragma unroll
            for (int r = 0; r < 8; ++r) ir[r] = (i0 + r < N) ? (i0 + r) : 0;
            for (int d = 0; d < 64; ++d) {
                float4 w4 = *(const float4*)&wst[d * 192 + o0];
                #pragma unroll
                for (int r = 0; r < 8; ++r) {
                    float yv = ys[ir[r] * XS + d];
                    acc[r][0] += yv * w4.x;
                    acc[r][1] += yv * w4.y;
                    acc[r][2] += yv * w4.z;
                    acc[r][3] += yv * w4.w;
                }
            }
            #pragma unroll
            for (int r = 0; r < 8; ++r) {
                if (i0 + r < N) {
                    float4 st;
                    st.x = acc[r][0]; st.y = acc[r][1]; st.z = acc[r][2]; st.w = acc[r][3];
                    *(float4*)&qkv[(i0 + r) * QS + o0] = st;
                }
            }
        }
    }
    __syncthreads();

    // ---- stage w_o + attention: per (head, query) streaming softmax ----
    for (int idx = t; idx < 64 * 64; idx += NTHREADS)
        wst[idx] = w_o[L * 64 * 64 + idx];
    for (int idx = t; idx < 8 * N; idx += NTHREADS) {
        int h = idx & 7, i = idx >> 3;
        const float4 q0 = *(const float4*)&qkv[i * QS + h * 8];
        const float4 q1 = *(const float4*)&qkv[i * QS + h * 8 + 4];
        float acc[8] = {0, 0, 0, 0, 0, 0, 0, 0};
        float den = 0.f;
        for (int j = 0; j < N; ++j) {
            const float4 k0 = *(const float4*)&qkv[j * QS + 64 + h * 8];
            const float4 k1 = *(const float4*)&qkv[j * QS + 64 + h * 8 + 4];
            float dot = q0.x * k0.x + q0.y * k0.y + q0.z * k0.z + q0.w * k0.w
                      + q1.x * k1.x + q1.y * k1.y + q1.z * k1.z + q1.w * k1.w;
            // logits are tiny (|s| < ~3): exp(s)/sum(exp(s)) == softmax-with-max exactly
            float pe = __expf(dot * 0.35355339059327373f);
            den += pe;
            const float4 v0 = *(const float4*)&qkv[j * QS + 128 + h * 8];
            const float4 v1 = *(const float4*)&qkv[j * QS + 128 + h * 8 + 4];
            acc[0] += pe * v0.x; acc[1] += pe * v0.y; acc[2] += pe * v0.z; acc[3] += pe * v0.w;
            acc[4] += pe * v1.x; acc[5] += pe * v1.y; acc[6] += pe * v1.z; acc[7] += pe * v1.w;
        }
        float dinv = 1.0f / den;
        #pragma unroll
        for (int e = 0; e < 8; ++e)
            ys[i * XS + h * 8 + e] = acc[e] * dinv;
    }
    __syncthreads();

    // ---- w_o GEMM + residual: xs += ys @ w_o + b_o. Tile MI=4 x NO=2 ----
    {
        constexpr int NTI = (N + 3) / 4;
        for (int tile = t; tile < NTI * 32; tile += NTHREADS) {
            int i0 = (tile / 32) * 4;
            int o0 = (tile % 32) * 2;
            float bo0 = b_o[L * 64 + o0], bo1 = b_o[L * 64 + o0 + 1];
            float acc[4][2];
            #pragma unroll
            for (int r = 0; r < 4; ++r) { acc[r][0] = bo0; acc[r][1] = bo1; }
            int ir[4];
            #pragma unroll
            for (int r = 0; r < 4; ++r) ir[r] = (i0 + r < N) ? (i0 + r) : 0;
            for (int d = 0; d < 64; ++d) {
                float2 wv = *(const float2*)&wst[d * 64 + o0];
                #pragma unroll
                for (int r = 0; r < 4; ++r) {
                    float yv = ys[ir[r] * XS + d];
                    acc[r][0] += yv * wv.x;
                    acc[r][1] += yv * wv.y;
                }
            }
            #pragma unroll
            for (int r = 0; r < 4; ++r) {
                if (i0 + r < N) {
                    xs[(i0 + r) * XS + o0]     += acc[r][0];
                    xs[(i0 + r) * XS + o0 + 1] += acc[r][1];
                }
            }
        }
    }
    __syncthreads();

    // ---- stage w1,w2 + LN2 ----
    for (int idx = t; idx < 512; idx += NTHREADS) wst[idx] = w1[L * 512 + idx];
    for (int idx = t; idx < 512; idx += NTHREADS) wst[512 + idx] = w2[L * 512 + idx];
    if (t < N) {
        float s1 = 0.f, s2 = 0.f;
        #pragma unroll
        for (int d = 0; d < 64; ++d) {
            float v = xs[t * XS + d];
            s1 += v; s2 += v * v;
        }
        float m = s1 * 0.015625f;
        float var = s2 * 0.015625f - m * m;
        float r = rsqrtf(var + 1e-5f);
        #pragma unroll
        for (int d = 0; d < 64; ++d) {
            float v = xs[t * XS + d];
            ys[t * XS + d] = (v - m) * r * ln2_g[L * 64 + d] + ln2_b[L * 64 + d];
        }
    }
    __syncthreads();

    // ---- MLP up + gelu: hbuf[N][8] ----
    for (int idx = t; idx < N * 8; idx += NTHREADS) {
        int j = idx & 7, i = idx >> 3;
        float acc = b1[L * 8 + j];
        #pragma unroll 8
        for (int d = 0; d < 64; ++d)
            acc += ys[i * XS + d] * wst[d * 8 + j];
        hbuf[i * 8 + j] = gelu_f(acc);
    }
    __syncthreads();

    // ---- MLP down + residual ----
    for (int idx = t; idx < N * 64; idx += NTHREADS) {
        int d = idx & 63, i = idx >> 6;
        float acc = b2[L * 64 + d];
        #pragma unroll
        for (int j = 0; j < 8; ++j)
            acc += hbuf[i * 8 + j] * wst[512 + j * 64 + d];
        xs[i * XS + d] += acc;
    }
    __syncthreads();

    // ---- crop (or final transpose+store) ----
    if (!LAST) {
        constexpr int PN = P - 2;
        for (int idx = t; idx < PN * PN * 64; idx += NTHREADS) {
            int i2 = idx >> 6, d = idx & 63;
            int r = i2 / PN, c = i2 % PN;
            ys[i2 * XS + d] = xs[((r + 1) * P + (c + 1)) * XS + d];
        }
        __syncthreads();
        for (int idx = t; idx < PN * PN * 64; idx += NTHREADS) {
            int i2 = idx >> 6, d = idx & 63;
            xs[i2 * XS + d] = ys[i2 * XS + d];
        }
        __syncthreads();
    } else {
        // out[b][d][r][c] = xs[r*3+c][d]; flat idx = d*9 + rc -> contiguous store
        for (int idx = t; idx < 576; idx += NTHREADS) {
            int d = idx / 9, rc = idx % 9;
            out[(size_t)b * 576 + idx] = xs[rc * XS + d];
        }
    }
}

__global__ __launch_bounds__(NTHREADS) void vit_kernel(
    const float* __restrict__ x_in,
    const float* __restrict__ w_qkv, const float* __restrict__ b_qkv,
    const float* __restrict__ w_o,   const float* __restrict__ b_o,
    const float* __restrict__ ln1_g, const float* __restrict__ ln1_b,
    const float* __restrict__ ln2_g, const float* __restrict__ ln2_b,
    const float* __restrict__ w1,    const float* __restrict__ b1,
    const float* __restrict__ w2,    const float* __restrict__ b2,
    float* __restrict__ out)
{
    __shared__ __align__(16) float xs[81 * 65];
    __shared__ __align__(16) float ys[81 * 65];
    __shared__ __align__(16) float qkv[81 * 196];
    __shared__ __align__(16) float wst[64 * 192];
    float* hbuf = qkv;  // reuse: qkv dead by the time MLP runs

    const int b = blockIdx.x;
    const int t = threadIdx.x;

    const float* xin = x_in + (size_t)b * 5184;
    for (int idx = t; idx < 5184; idx += NTHREADS) {
        int i = idx >> 6, d = idx & 63;
        xs[i * 65 + d] = xin[idx];
    }
    __syncthreads();

    layer_fn<81, 9, 0, false>(xs, ys, qkv, wst, hbuf, w_qkv, b_qkv, w_o, b_o,
                              ln1_g, ln1_b, ln2_g, ln2_b, w1, b1, w2, b2, out, b, t);
    layer_fn<49, 7, 1, false>(xs, ys, qkv, wst, hbuf, w_qkv, b_qkv, w_o, b_o,
                              ln1_g, ln1_b, ln2_g, ln2_b, w1, b1, w2, b2, out, b, t);
    layer_fn<25, 5, 2, false>(xs, ys, qkv, wst, hbuf, w_qkv, b_qkv, w_o, b_o,
                              ln1_g, ln1_b, ln2_g, ln2_b, w1, b1, w2, b2, out, b, t);
    layer_fn<9, 3, 3, true>(xs, ys, qkv, wst, hbuf, w_qkv, b_qkv, w_o, b_o,
                            ln1_g, ln1_b, ln2_g, ln2_b, w1, b1, w2, b2, out, b, t);
}

extern "C" void kernel_launch(void* const* d_in, const int* in_sizes, int n_in,
                              void* d_out, int out_size, void* d_ws, size_t ws_size,
                              hipStream_t stream) {
    (void)n_in; (void)out_size; (void)d_ws; (void)ws_size;
    const float* x     = (const float*)d_in[0];
    const float* w_qkv = (const float*)d_in[1];
    const float* b_qkv = (const float*)d_in[2];
    const float* w_o   = (const float*)d_in[3];
    const float* b_o   = (const float*)d_in[4];
    const float* ln1_g = (const float*)d_in[5];
    const float* ln1_b = (const float*)d_in[6];
    const float* ln2_g = (const float*)d_in[7];
    const float* ln2_b = (const float*)d_in[8];
    const float* w1    = (const float*)d_in[9];
    const float* b1    = (const float*)d_in[10];
    const float* w2    = (const float*)d_in[11];
    const float* w2b   = (const float*)d_in[12];

    int B = in_sizes[0] / (81 * 64);
    vit_kernel<<<dim3(B), dim3(NTHREADS), 0, stream>>>(
        x, w_qkv, b_qkv, w_o, b_o, ln1_g, ln1_b, ln2_g, ln2_b,
        w1, b1, w2, w2b, (float*)d_out);
}

// Round 2
// 1062.791 us; speedup vs baseline: 2.2063x; 2.2063x over previous
//
#include <hip/hip_runtime.h>
#include <math.h>

#define NT 512

typedef __attribute__((ext_vector_type(8))) short short8v;
typedef __attribute__((ext_vector_type(4))) float f32x4;

__device__ __forceinline__ unsigned short f2bf(float x) {
    unsigned u = __float_as_uint(x);
    unsigned r = ((u >> 16) & 1u) + 0x7FFFu;
    return (unsigned short)((u + r) >> 16);
}
__device__ __forceinline__ unsigned pack2bf(float a, float b) {
    return (unsigned)f2bf(a) | ((unsigned)f2bf(b) << 16);
}
__device__ __forceinline__ float gelu_f(float x) {
    return 0.5f * x * (1.0f + erff(x * 0.70710678118654752f));
}
__device__ __forceinline__ f32x4 mfma16(short8v a, short8v b, f32x4 c) {
    return __builtin_amdgcn_mfma_f32_16x16x32_bf16(a, b, c, 0, 0, 0);
}

// LDS layouts (strides in elements):
//  xs  fp32 [81][65]           residual (stride 65: conflict-free row scans)
//  ybf bf16 [96][72]           LN out / attn out (A-operand; rows>=N zeroed)
//  qbf bf16 [96][72]           q channels; later reused for w_oT/w1T/w2T/h
//  kbf bf16 [96][72]           k channels
//  vT  bf16 [72][104]          v transposed [channel][token]; pad cols zeroed
//  U   bf16 [4*96*104]         wqkvT staging, then P buffers (4 heads/round)
//  dbuf f32 [4][96]            softmax reciprocal denominators
template<int N, int P, int L, bool LAST>
__device__ __forceinline__ void layer_fn(
    float* __restrict__ xs, short* __restrict__ ybf, short* __restrict__ qbf,
    short* __restrict__ kbf, short* __restrict__ vT, short* __restrict__ U,
    float* __restrict__ dbuf,
    const float* __restrict__ w_qkv, const float* __restrict__ b_qkv,
    const float* __restrict__ w_o,   const float* __restrict__ b_o,
    const float* __restrict__ ln1_g, const float* __restrict__ ln1_b,
    const float* __restrict__ ln2_g, const float* __restrict__ ln2_b,
    const float* __restrict__ w1,    const float* __restrict__ b1,
    const float* __restrict__ w2,    const float* __restrict__ b2,
    float* __restrict__ out, int b, int t)
{
    constexpr int Mt = (N + 15) / 16;   // 16-row M tiles
    constexpr int KS = (N + 31) / 32;   // PV K-steps (j in [0, 32*KS))
    constexpr int JT = 2 * KS;          // scores j-tiles (covers PV K range)
    const int wv = t >> 6;
    const int l = t & 63;
    const int lr = l & 15;
    const int lq = l >> 4;
    short8v zero8 = {};
    f32x4 zero4 = {0.f, 0.f, 0.f, 0.f};

    // ---- phase 1: stage wqkvT (bf16, transposed), LN1 -> ybf, zero vT pad cols
    for (int idx = t; idx < 64 * 192; idx += NT) {
        int d = idx / 192, c = idx % 192;
        U[c * 72 + d] = (short)f2bf(w_qkv[L * 12288 + idx]);
    }
    {
        constexpr int ZC = 32 * KS - N;  // pad columns to zero
        for (int idx = t; idx < 64 * ZC; idx += NT) {
            int r = idx / ZC, c = N + idx % ZC;
            vT[r * 104 + c] = 0;
        }
    }
    if (t < 96) {
        if (t < N) {
            float s1 = 0.f, s2 = 0.f;
            #pragma unroll 4
            for (int d = 0; d < 64; ++d) { float v = xs[t * 65 + d]; s1 += v; s2 += v * v; }
            float m = s1 * 0.015625f;
            float r = rsqrtf(s2 * 0.015625f - m * m + 1e-5f);
            #pragma unroll 4
            for (int d = 0; d < 64; ++d) {
                float v = (xs[t * 65 + d] - m) * r * ln1_g[L * 64 + d] + ln1_b[L * 64 + d];
                ybf[t * 72 + d] = (short)f2bf(v);
            }
        } else {
            #pragma unroll 4
            for (int d = 0; d < 64; ++d) ybf[t * 72 + d] = 0;
        }
    }
    __syncthreads();

    // ---- phase 2: qkv GEMM (M=N pad 16*Mt, N'=192, K=64) -> qbf,kbf,vT
    for (int u = wv; u < Mt * 4; u += 8) {
        int mt = u >> 2, c3 = (u & 3) * 3;
        short8v a0 = *(const short8v*)&ybf[(lr + 16 * mt) * 72 + lq * 8];
        short8v a1 = *(const short8v*)&ybf[(lr + 16 * mt) * 72 + lq * 8 + 32];
        for (int cc = 0; cc < 3; ++cc) {
            int ct = c3 + cc;
            short8v b0 = *(const short8v*)&U[(lr + 16 * ct) * 72 + lq * 8];
            short8v b1v = *(const short8v*)&U[(lr + 16 * ct) * 72 + lq * 8 + 32];
            f32x4 acc = zero4;
            acc = mfma16(a0, b0, acc);
            acc = mfma16(a1, b1v, acc);
            int c = 16 * ct + lr;
            float bias = b_qkv[L * 192 + c];
            #pragma unroll
            for (int rg = 0; rg < 4; ++rg) {
                int i = 16 * mt + lq * 4 + rg;
                float val = acc[rg] + bias;
                if (ct < 4)      qbf[i * 72 + c] = (short)f2bf(val);
                else if (ct < 8) kbf[i * 72 + (c - 64)] = (short)f2bf(val);
                else if (i < N)  vT[(c - 128) * 104 + i] = (short)f2bf(val);
            }
        }
    }
    __syncthreads();

    // ---- attention: 2 rounds x 4 heads; S^T = K·Q^T via swapped MFMA operands
    for (int rnd = 0; rnd < 2; ++rnd) {
        int h0 = rnd * 4;
        // scores + softmax -> P (unnormalized, bf16), dbuf = 1/den
        for (int u = wv; u < 4 * Mt; u += 8) {
            int hx = u & 3, it = u >> 2, h = h0 + hx;
            short8v bq = zero8;
            if (l < 16) bq = *(const short8v*)&qbf[(lr + 16 * it) * 72 + h * 8];
            f32x4 acc[JT];
            #pragma unroll
            for (int jt = 0; jt < JT; ++jt) {
                short8v ak = zero8;
                if (l < 16) ak = *(const short8v*)&kbf[(lr + 16 * jt) * 72 + h * 8];
                acc[jt] = mfma16(ak, bq, zero4);
            }
            float pv[JT][4];
            float psum = 0.f;
            #pragma unroll
            for (int jt = 0; jt < JT; ++jt) {
                #pragma unroll
                for (int rg = 0; rg < 4; ++rg) {
                    int j = 16 * jt + lq * 4 + rg;
                    float e = __expf(acc[jt][rg] * 0.35355339059327373f);
                    e = (j < N) ? e : 0.f;   // mask invalid keys (and NaN garbage)
                    pv[jt][rg] = e;
                    psum += e;
                }
            }
            float d1 = psum + __shfl_xor(psum, 16);
            float den = d1 + __shfl_xor(d1, 32);
            int i = lr + 16 * it;
            if (l < 16) dbuf[hx * 96 + i] = 1.0f / den;
            short* Pb = U + hx * 9984;
            #pragma unroll
            for (int jt = 0; jt < JT; ++jt) {
                int jb = 16 * jt + lq * 4;
                *(unsigned*)&Pb[i * 104 + jb]     = pack2bf(pv[jt][0], pv[jt][1]);
                *(unsigned*)&Pb[i * 104 + jb + 2] = pack2bf(pv[jt][2], pv[jt][3]);
            }
        }
        __syncthreads();
        // PV: out[i][d] = sum_j P[i][j] * V[j][d]
        for (int u = wv; u < 4 * Mt; u += 8) {
            int hx = u & 3, mt = u >> 2, h = h0 + hx;
            const short* Pb = U + hx * 9984;
            f32x4 acc = zero4;
            #pragma unroll
            for (int ks = 0; ks < KS; ++ks) {
                short8v ap = *(const short8v*)&Pb[(lr + 16 * mt) * 104 + lq * 8 + 32 * ks];
                short8v bv = *(const short8v*)&vT[(h * 8 + lr) * 104 + lq * 8 + 32 * ks];
                acc = mfma16(ap, bv, acc);
            }
            if (lr < 8) {
                #pragma unroll
                for (int rg = 0; rg < 4; ++rg) {
                    int i = 16 * mt + lq * 4 + rg;
                    if (i < N) {
                        float rd = dbuf[hx * 96 + i];
                        ybf[i * 72 + h * 8 + lr] = (short)f2bf(acc[rg] * rd);
                    }
                }
            }
        }
        if (rnd == 1) {
            // qbf now dead: stage w_oT [64][72] @0, w1T [16][72] @4608,
            // w2T [64][8] @5760  (h [96][24] will live @6272)
            for (int idx = t; idx < 4096; idx += NT) {
                int d = idx >> 6, c = idx & 63;
                qbf[c * 72 + d] = (short)f2bf(w_o[L * 4096 + idx]);
            }
            for (int idx = t; idx < 16 * 72; idx += NT) {
                int j = idx / 72, d = idx % 72;
                qbf[4608 + idx] = (j < 8 && d < 64) ? (short)f2bf(w1[L * 512 + d * 8 + j]) : (short)0;
            }
            for (int idx = t; idx < 512; idx += NT) {
                int c = idx >> 3, j = idx & 7;
                qbf[5760 + c * 8 + j] = (short)f2bf(w2[L * 512 + j * 64 + c]);
            }
        }
        __syncthreads();
    }

    // ---- w_o GEMM + residual into xs
    for (int u = wv; u < Mt * 4; u += 8) {
        int mt = u >> 2, ct = u & 3;
        short8v a0 = *(const short8v*)&ybf[(lr + 16 * mt) * 72 + lq * 8];
        short8v a1 = *(const short8v*)&ybf[(lr + 16 * mt) * 72 + lq * 8 + 32];
        short8v b0 = *(const short8v*)&qbf[(lr + 16 * ct) * 72 + lq * 8];
        short8v b1v = *(const short8v*)&qbf[(lr + 16 * ct) * 72 + lq * 8 + 32];
        f32x4 acc = zero4;
        acc = mfma16(a0, b0, acc);
        acc = mfma16(a1, b1v, acc);
        int c = 16 * ct + lr;
        float bias = b_o[L * 64 + c];
        #pragma unroll
        for (int rg = 0; rg < 4; ++rg) {
            int i = 16 * mt + lq * 4 + rg;
            if (i < N) xs[i * 65 + c] += acc[rg] + bias;
        }
    }
    __syncthreads();

    // ---- LN2 -> ybf
    if (t < 96) {
        if (t < N) {
            float s1 = 0.f, s2 = 0.f;
            #pragma unroll 4
            for (int d = 0; d < 64; ++d) { float v = xs[t * 65 + d]; s1 += v; s2 += v * v; }
            float m = s1 * 0.015625f;
            float r = rsqrtf(s2 * 0.015625f - m * m + 1e-5f);
            #pragma unroll 4
            for (int d = 0; d < 64; ++d) {
                float v = (xs[t * 65 + d] - m) * r * ln2_g[L * 64 + d] + ln2_b[L * 64 + d];
                ybf[t * 72 + d] = (short)f2bf(v);
            }
        } else {
            #pragma unroll 4
            for (int d = 0; d < 64; ++d) ybf[t * 72 + d] = 0;
        }
    }
    __syncthreads();

    // ---- MLP up: h = gelu(ybf @ w1 + b1), 8 valid cols
    {
        const short* w1T = qbf + 4608;
        short* hb = qbf + 6272;
        for (int u = wv; u < Mt; u += 8) {
            int mt = u;
            short8v a0 = *(const short8v*)&ybf[(lr + 16 * mt) * 72 + lq * 8];
            short8v a1 = *(const short8v*)&ybf[(lr + 16 * mt) * 72 + lq * 8 + 32];
            short8v b0 = *(const short8v*)&w1T[lr * 72 + lq * 8];
            short8v b1v = *(const short8v*)&w1T[lr * 72 + lq * 8 + 32];
            f32x4 acc = zero4;
            acc = mfma16(a0, b0, acc);
            acc = mfma16(a1, b1v, acc);
            if (lr < 8) {
                float bias = b1[L * 8 + lr];
                #pragma unroll
                for (int rg = 0; rg < 4; ++rg) {
                    int i = 16 * mt + lq * 4 + rg;
                    hb[i * 24 + lr] = (short)f2bf(gelu_f(acc[rg] + bias));
                }
            }
        }
    }
    __syncthreads();

    // ---- MLP down + residual: xs += h @ w2 + b2  (K=8, lanes<16 only)
    {
        const short* w2T = qbf + 5760;
        const short* hb = qbf + 6272;
        for (int u = wv; u < Mt * 4; u += 8) {
            int mt = u >> 2, ct = u & 3;
            short8v a = zero8, bb = zero8;
            if (l < 16) {
                a  = *(const short8v*)&hb[(lr + 16 * mt) * 24];
                bb = *(const short8v*)&w2T[(lr + 16 * ct) * 8];
            }
            f32x4 acc = zero4;
            acc = mfma16(a, bb, acc);
            int c = 16 * ct + lr;
            float bias = b2[L * 64 + c];
            #pragma unroll
            for (int rg = 0; rg < 4; ++rg) {
                int i = 16 * mt + lq * 4 + rg;
                if (i < N) xs[i * 65 + c] += acc[rg] + bias;
            }
        }
    }
    __syncthreads();

    // ---- crop (or final transpose + store)
    if (!LAST) {
        constexpr int PN = P - 2;
        constexpr int CNT = PN * PN * 64;
        constexpr int NREG = (CNT + NT - 1) / NT;
        float vals[NREG];
        #pragma unroll
        for (int k = 0; k < NREG; ++k) {
            int idx = t + k * NT;
            if (idx < CNT) {
                int i2 = idx >> 6, d = idx & 63;
                int r = i2 / PN, c = i2 % PN;
                vals[k] = xs[((r + 1) * P + (c + 1)) * 65 + d];
            }
        }
        __syncthreads();
        #pragma unroll
        for (int k = 0; k < NREG; ++k) {
            int idx = t + k * NT;
            if (idx < CNT) {
                int i2 = idx >> 6, d = idx & 63;
                xs[i2 * 65 + d] = vals[k];
            }
        }
        __syncthreads();
    } else {
        for (int idx = t; idx < 576; idx += NT) {
            int d = idx / 9, rc = idx % 9;
            out[(size_t)b * 576 + idx] = xs[rc * 65 + d];
        }
    }
}

__global__ __launch_bounds__(NT) void vit_kernel(
    const float* __restrict__ x_in,
    const float* __restrict__ w_qkv, const float* __restrict__ b_qkv,
    const float* __restrict__ w_o,   const float* __restrict__ b_o,
    const float* __restrict__ ln1_g, const float* __restrict__ ln1_b,
    const float* __restrict__ ln2_g, const float* __restrict__ ln2_b,
    const float* __restrict__ w1,    const float* __restrict__ b1,
    const float* __restrict__ w2,    const float* __restrict__ b2,
    float* __restrict__ out)
{
    __shared__ __align__(16) float xs[81 * 65];
    __shared__ __align__(16) short ybf[96 * 72];
    __shared__ __align__(16) short qbf[96 * 72];
    __shared__ __align__(16) short kbf[96 * 72];
    __shared__ __align__(16) short vT[72 * 104];
    __shared__ __align__(16) short U[4 * 96 * 104];
    __shared__ __align__(16) float dbuf[4 * 96];

    const int b = blockIdx.x;
    const int t = threadIdx.x;

    const float* xin = x_in + (size_t)b * 5184;
    for (int idx = t; idx < 5184; idx += NT) {
        int i = idx >> 6, d = idx & 63;
        xs[i * 65 + d] = xin[idx];
    }
    __syncthreads();

    layer_fn<81, 9, 0, false>(xs, ybf, qbf, kbf, vT, U, dbuf, w_qkv, b_qkv, w_o, b_o,
                              ln1_g, ln1_b, ln2_g, ln2_b, w1, b1, w2, b2, out, b, t);
    layer_fn<49, 7, 1, false>(xs, ybf, qbf, kbf, vT, U, dbuf, w_qkv, b_qkv, w_o, b_o,
                              ln1_g, ln1_b, ln2_g, ln2_b, w1, b1, w2, b2, out, b, t);
    layer_fn<25, 5, 2, false>(xs, ybf, qbf, kbf, vT, U, dbuf, w_qkv, b_qkv, w_o, b_o,
                              ln1_g, ln1_b, ln2_g, ln2_b, w1, b1, w2, b2, out, b, t);
    layer_fn<9, 3, 3, true>(xs, ybf, qbf, kbf, vT, U, dbuf, w_qkv, b_qkv, w_o, b_o,
                            ln1_g, ln1_b, ln2_g, ln2_b, w1, b1, w2, b2, out, b, t);
}

extern "C" void kernel_launch(void* const* d_in, const int* in_sizes, int n_in,
                              void* d_out, int out_size, void* d_ws, size_t ws_size,
                              hipStream_t stream) {
    (void)n_in; (void)out_size; (void)d_ws; (void)ws_size;
    const float* x     = (const float*)d_in[0];
    const float* w_qkv = (const float*)d_in[1];
    const float* b_qkv = (const float*)d_in[2];
    const float* w_o   = (const float*)d_in[3];
    const float* b_o   = (const float*)d_in[4];
    const float* ln1_g = (const float*)d_in[5];
    const float* ln1_b = (const float*)d_in[6];
    const float* ln2_g = (const float*)d_in[7];
    const float* ln2_b = (const float*)d_in[8];
    const float* w1    = (const float*)d_in[9];
    const float* b1    = (const float*)d_in[10];
    const float* w2    = (const float*)d_in[11];
    const float* b2    = (const float*)d_in[12];

    int B = in_sizes[0] / (81 * 64);
    vit_kernel<<<dim3(B), dim3(NT), 0, stream>>>(
        x, w_qkv, b_qkv, w_o, b_o, ln1_g, ln1_b, ln2_g, ln2_b,
        w1, b1, w2, b2, (float*)d_out);
}

// Round 4
// 551.993 us; speedup vs baseline: 4.2479x; 1.9254x over previous
//
#include <hip/hip_runtime.h>
#include <math.h>

#define NT 512

typedef __attribute__((ext_vector_type(8))) short short8v;
typedef __attribute__((ext_vector_type(4))) short short4v;
typedef __attribute__((ext_vector_type(4))) float f32x4;
typedef __attribute__((ext_vector_type(2))) unsigned uint2v;
typedef __attribute__((ext_vector_type(4))) unsigned uint4v;

__device__ __forceinline__ unsigned short f2bf(float x) {
    unsigned u = __float_as_uint(x);
    unsigned r = ((u >> 16) & 1u) + 0x7FFFu;
    return (unsigned short)((u + r) >> 16);
}
__device__ __forceinline__ unsigned pack2bf(float a, float b) {
    return (unsigned)f2bf(a) | ((unsigned)f2bf(b) << 16);
}
__device__ __forceinline__ float gelu_f(float x) {
    return 0.5f * x * (1.0f + erff(x * 0.70710678118654752f));
}
__device__ __forceinline__ f32x4 mfma32(short8v a, short8v b, f32x4 c) {
    return __builtin_amdgcn_mfma_f32_16x16x32_bf16(a, b, c, 0, 0, 0);
}

// ws layout (bf16 shorts): wqkvT[L][192][64] @0 ; woT[L][64][64] @49152 ;
//                          w1T[L][16][64] @65536 (rows j>=8 zero) ; w2T[L][64][8] @69632
#define WS_WO 49152
#define WS_W1 65536
#define WS_W2 69632
#define WS_TOT 71680

__global__ __launch_bounds__(256) void prep_kernel(
    const float* __restrict__ w_qkv, const float* __restrict__ w_o,
    const float* __restrict__ w1, const float* __restrict__ w2,
    short* __restrict__ ws)
{
    int idx = blockIdx.x * 256 + threadIdx.x;
    if (idx < WS_WO) {
        int l = idx / 12288, r = idx % 12288, c = r >> 6, d = r & 63;
        ws[idx] = (short)f2bf(w_qkv[l * 12288 + d * 192 + c]);
    } else if (idx < WS_W1) {
        int k = idx - WS_WO; int l = k / 4096, r = k % 4096, c = r >> 6, d = r & 63;
        ws[idx] = (short)f2bf(w_o[l * 4096 + d * 64 + c]);
    } else if (idx < WS_W2) {
        int k = idx - WS_W1; int l = k / 1024, r = k % 1024, j = r >> 6, d = r & 63;
        ws[idx] = (j < 8) ? (short)f2bf(w1[l * 512 + d * 8 + j]) : (short)0;
    } else if (idx < WS_TOT) {
        int k = idx - WS_W2; int l = k / 512, r = k % 512, c = r >> 3, j = r & 7;
        ws[idx] = (short)f2bf(w2[l * 512 + j * 64 + c]);
    }
}

// LDS: xs fp32 [81][66]; ybf/qbf/kbf bf16 [96][72]; vT bf16 [64][104].
// hb (MLP hidden, [96][8]) aliases qbf (dead after attention).
template<int N, int P, int L, bool LAST>
__device__ __forceinline__ void layer_fn(
    float* __restrict__ xs, short* __restrict__ ybf, short* __restrict__ qbf,
    short* __restrict__ kbf, short* __restrict__ vT,
    const short* __restrict__ ws,
    const float* __restrict__ b_qkv, const float* __restrict__ b_o,
    const float* __restrict__ ln1_g, const float* __restrict__ ln1_b,
    const float* __restrict__ ln2_g, const float* __restrict__ ln2_b,
    const float* __restrict__ b1,    const float* __restrict__ b2,
    float* __restrict__ out, int b, int t)
{
    constexpr int Mt = (N + 15) / 16;
    constexpr float SC = 0.35355339059327373f;
    const int wv = t >> 6, l = t & 63, lr = l & 15, lq = l >> 4;
    short8v zero8 = {};
    f32x4 zero4 = {0.f, 0.f, 0.f, 0.f};

    // ---- LN1 -> ybf (token per thread; pad rows zeroed) ----
    if (t < 16 * Mt) {
        if (t < N) {
            float s1 = 0.f, s2 = 0.f;
            #pragma unroll 4
            for (int d = 0; d < 64; ++d) { float v = xs[t * 66 + d]; s1 += v; s2 += v * v; }
            float m = s1 * 0.015625f;
            float r = rsqrtf(s2 * 0.015625f - m * m + 1e-5f);
            #pragma unroll 4
            for (int d = 0; d < 64; ++d) {
                float v = (xs[t * 66 + d] - m) * r * ln1_g[L * 64 + d] + ln1_b[L * 64 + d];
                ybf[t * 72 + d] = (short)f2bf(v);
            }
        } else {
            #pragma unroll 4
            for (int d = 0; d < 64; ++d) ybf[t * 72 + d] = 0;
        }
    }
    __syncthreads();

    // ---- qkv GEMM: B-frags streamed from global wqkvT ----
    {
        const short* wqL = ws + L * 12288;
        for (int u = wv; u < Mt * 12; u += 8) {
            int mt = u / 12, ct = u - mt * 12;
            const short* ar = &ybf[(16 * mt + lr) * 72 + lq * 8];
            short8v a0 = *(const short8v*)ar;
            short8v a1 = *(const short8v*)(ar + 32);
            const short* br = &wqL[(16 * ct + lr) * 64 + lq * 8];
            short8v b0 = *(const short8v*)br;
            short8v b1v = *(const short8v*)(br + 32);
            f32x4 acc = mfma32(a0, b0, zero4);
            acc = mfma32(a1, b1v, acc);
            int c = 16 * ct + lr;
            float bias = b_qkv[L * 192 + c];
            if (ct < 4) {
                #pragma unroll
                for (int rg = 0; rg < 4; ++rg)
                    qbf[(16 * mt + lq * 4 + rg) * 72 + c] = (short)f2bf(acc[rg] + bias);
            } else if (ct < 8) {
                #pragma unroll
                for (int rg = 0; rg < 4; ++rg)
                    kbf[(16 * mt + lq * 4 + rg) * 72 + (c - 64)] = (short)f2bf(acc[rg] + bias);
            } else {
                #pragma unroll
                for (int rg = 0; rg < 4; ++rg) {
                    int i = 16 * mt + lq * 4 + rg;
                    if (i < N) vT[(c - 128) * 104 + i] = (short)f2bf(acc[rg] + bias);
                }
            }
        }
    }
    __syncthreads();

    // ---- attention: fully in-wave (no internal barriers). S^T = K·Q^T ----
    for (int u = wv; u < 8 * Mt; u += 8) {
        int h = u & 7, mt = u >> 3;
        short8v bq = zero8;
        if (l < 16) bq = *(const short8v*)&qbf[(16 * mt + lr) * 72 + h * 8];
        f32x4 acc[Mt];
        #pragma unroll
        for (int jt = 0; jt < Mt; ++jt) {
            short8v ak = zero8;
            if (l < 16) ak = *(const short8v*)&kbf[(16 * jt + lr) * 72 + h * 8];
            acc[jt] = mfma32(ak, bq, zero4);
        }
        // in-register softmax (no max-subtract: logits bounded ~|3|)
        float psum = 0.f;
        #pragma unroll
        for (int jt = 0; jt < Mt; ++jt) {
            #pragma unroll
            for (int rg = 0; rg < 4; ++rg) {
                int j = 16 * jt + lq * 4 + rg;
                float e = __expf(acc[jt][rg] * SC);
                e = (j < N) ? e : 0.f;
                acc[jt][rg] = e;
                psum += e;
            }
        }
        float den = psum + __shfl_xor(psum, 16);
        den += __shfl_xor(den, 32);
        float dinv = 1.0f / den;
        unsigned pk[Mt][2];
        #pragma unroll
        for (int jt = 0; jt < Mt; ++jt) {
            pk[jt][0] = pack2bf(acc[jt][0] * dinv, acc[jt][1] * dinv);
            pk[jt][1] = pack2bf(acc[jt][2] * dinv, acc[jt][3] * dinv);
        }
        // PV: out^T = V^T · P^T ; register P^T is already the B-fragment
        int hh = h >> 1;
        f32x4 po = zero4;
#if __has_builtin(__builtin_amdgcn_mfma_f32_16x16x16bf16_1k)
        #pragma unroll
        for (int jt = 0; jt < Mt; ++jt) {
            short4v av = *(const short4v*)&vT[(16 * hh + lr) * 104 + 16 * jt + lq * 4];
            uint2v pw; pw.x = pk[jt][0]; pw.y = pk[jt][1];
            short4v bv = __builtin_bit_cast(short4v, pw);
            po = __builtin_amdgcn_mfma_f32_16x16x16bf16_1k(av, bv, po, 0, 0, 0);
        }
#else
        // fallback: 16x16x32 with B built via ds_bpermute over tile pairs
        #pragma unroll
        for (int ks = 0; ks < (Mt + 1) / 2; ++ks) {
            int t1ok = (2 * ks + 1) < Mt;
            unsigned pA0 = pk[2 * ks][0], pA1 = pk[2 * ks][1];
            unsigned pB0 = t1ok ? pk[2 * ks + 1][0] : 0u;
            unsigned pB1 = t1ok ? pk[2 * ks + 1][1] : 0u;
            int i01 = ((((lq & 1) * 2) * 16) + lr) * 4;
            int i23 = ((((lq & 1) * 2 + 1) * 16) + lr) * 4;
            unsigned w0a = (unsigned)__builtin_amdgcn_ds_bpermute(i01, (int)pA0);
            unsigned w0b = (unsigned)__builtin_amdgcn_ds_bpermute(i01, (int)pB0);
            unsigned w1a = (unsigned)__builtin_amdgcn_ds_bpermute(i01, (int)pA1);
            unsigned w1b = (unsigned)__builtin_amdgcn_ds_bpermute(i01, (int)pB1);
            unsigned w2a = (unsigned)__builtin_amdgcn_ds_bpermute(i23, (int)pA0);
            unsigned w2b = (unsigned)__builtin_amdgcn_ds_bpermute(i23, (int)pB0);
            unsigned w3a = (unsigned)__builtin_amdgcn_ds_bpermute(i23, (int)pA1);
            unsigned w3b = (unsigned)__builtin_amdgcn_ds_bpermute(i23, (int)pB1);
            uint4v wv4;
            wv4.x = (lq >> 1) ? w0b : w0a;
            wv4.y = (lq >> 1) ? w1b : w1a;
            wv4.z = (lq >> 1) ? w2b : w2a;
            wv4.w = (lq >> 1) ? w3b : w3a;
            short8v bv = __builtin_bit_cast(short8v, wv4);
            short8v av = *(const short8v*)&vT[(16 * hh + lr) * 104 + 32 * ks + lq * 8];
            po = mfma32(av, bv, po);
        }
#endif
        if ((lq >> 1) == (h & 1)) {
            int i = 16 * mt + lr;
            if (i < N) {
                #pragma unroll
                for (int rg = 0; rg < 4; ++rg)
                    ybf[i * 72 + h * 8 + (lq & 1) * 4 + rg] = (short)f2bf(po[rg]);
            }
        }
    }
    __syncthreads();

    // ---- w_o GEMM + residual into xs ----
    {
        const short* woL = ws + WS_WO + L * 4096;
        for (int u = wv; u < Mt * 4; u += 8) {
            int mt = u >> 2, ct = u & 3;
            const short* ar = &ybf[(16 * mt + lr) * 72 + lq * 8];
            short8v a0 = *(const short8v*)ar;
            short8v a1 = *(const short8v*)(ar + 32);
            const short* br = &woL[(16 * ct + lr) * 64 + lq * 8];
            short8v b0 = *(const short8v*)br;
            short8v b1v = *(const short8v*)(br + 32);
            f32x4 acc = mfma32(a0, b0, zero4);
            acc = mfma32(a1, b1v, acc);
            int c = 16 * ct + lr;
            float bias = b_o[L * 64 + c];
            #pragma unroll
            for (int rg = 0; rg < 4; ++rg) {
                int i = 16 * mt + lq * 4 + rg;
                if (i < N) xs[i * 66 + c] += acc[rg] + bias;
            }
        }
    }
    __syncthreads();

    // ---- LN2 -> ybf ----
    if (t < 16 * Mt) {
        if (t < N) {
            float s1 = 0.f, s2 = 0.f;
            #pragma unroll 4
            for (int d = 0; d < 64; ++d) { float v = xs[t * 66 + d]; s1 += v; s2 += v * v; }
            float m = s1 * 0.015625f;
            float r = rsqrtf(s2 * 0.015625f - m * m + 1e-5f);
            #pragma unroll 4
            for (int d = 0; d < 64; ++d) {
                float v = (xs[t * 66 + d] - m) * r * ln2_g[L * 64 + d] + ln2_b[L * 64 + d];
                ybf[t * 72 + d] = (short)f2bf(v);
            }
        } else {
            #pragma unroll 4
            for (int d = 0; d < 64; ++d) ybf[t * 72 + d] = 0;
        }
    }
    __syncthreads();

    // ---- MLP up: hb = gelu(ybf @ w1 + b1) ----
    short* hb = qbf;  // qbf dead after attention
    {
        const short* w1L = ws + WS_W1 + L * 1024;
        for (int u = wv; u < Mt; u += 8) {
            const short* ar = &ybf[(16 * u + lr) * 72 + lq * 8];
            short8v a0 = *(const short8v*)ar;
            short8v a1 = *(const short8v*)(ar + 32);
            const short* br = &w1L[lr * 64 + lq * 8];
            short8v b0 = *(const short8v*)br;
            short8v b1v = *(const short8v*)(br + 32);
            f32x4 acc = mfma32(a0, b0, zero4);
            acc = mfma32(a1, b1v, acc);
            if (lr < 8) {
                float bg = b1[L * 8 + lr];
                #pragma unroll
                for (int rg = 0; rg < 4; ++rg)
                    hb[(16 * u + lq * 4 + rg) * 8 + lr] = (short)f2bf(gelu_f(acc[rg] + bg));
            }
        }
    }
    __syncthreads();

    // ---- MLP down + residual (K=8) ----
    {
        const short* w2L = ws + WS_W2 + L * 512;
        for (int u = wv; u < Mt * 4; u += 8) {
            int mt = u >> 2, ct = u & 3;
            short8v a = zero8, bb = zero8;
            if (l < 16) {
                a  = *(const short8v*)&hb[(16 * mt + lr) * 8];
                bb = *(const short8v*)&w2L[(16 * ct + lr) * 8];
            }
            f32x4 acc = mfma32(a, bb, zero4);
            int c = 16 * ct + lr;
            float bias = b2[L * 64 + c];
            #pragma unroll
            for (int rg = 0; rg < 4; ++rg) {
                int i = 16 * mt + lq * 4 + rg;
                if (i < N) xs[i * 66 + c] += acc[rg] + bias;
            }
        }
    }
    __syncthreads();

    // ---- crop (or final transpose + store) ----
    if (!LAST) {
        constexpr int PN = P - 2;
        constexpr int CNT = PN * PN * 64;
        constexpr int NREG = (CNT + NT - 1) / NT;
        float vals[NREG];
        #pragma unroll
        for (int k = 0; k < NREG; ++k) {
            int idx = t + k * NT;
            if (idx < CNT) {
                int i2 = idx >> 6, d = idx & 63;
                int r = i2 / PN, c = i2 % PN;
                vals[k] = xs[((r + 1) * P + (c + 1)) * 66 + d];
            }
        }
        __syncthreads();
        #pragma unroll
        for (int k = 0; k < NREG; ++k) {
            int idx = t + k * NT;
            if (idx < CNT) {
                int i2 = idx >> 6, d = idx & 63;
                xs[i2 * 66 + d] = vals[k];
            }
        }
        __syncthreads();
    } else {
        for (int idx = t; idx < 576; idx += NT) {
            int d = idx / 9, rc = idx % 9;
            out[(size_t)b * 576 + idx] = xs[rc * 66 + d];
        }
    }
}

__global__ __launch_bounds__(NT, 4) void vit_kernel(
    const float* __restrict__ x_in, const short* __restrict__ ws,
    const float* __restrict__ b_qkv, const float* __restrict__ b_o,
    const float* __restrict__ ln1_g, const float* __restrict__ ln1_b,
    const float* __restrict__ ln2_g, const float* __restrict__ ln2_b,
    const float* __restrict__ b1,    const float* __restrict__ b2,
    float* __restrict__ out)
{
    __shared__ __align__(16) float xs[81 * 66];
    __shared__ __align__(16) short ybf[96 * 72];
    __shared__ __align__(16) short qbf[96 * 72];
    __shared__ __align__(16) short kbf[96 * 72];
    __shared__ __align__(16) short vT[64 * 104];

    const int b = blockIdx.x;
    const int t = threadIdx.x;

    // zero vT once: pad columns [N,16*Mt) are read by PV (x zero-masked P),
    // and 0 * uninitialized(NaN) = NaN inside MFMA -> must be finite.
    for (int idx = t; idx < 64 * 104; idx += NT) vT[idx] = 0;

    const float* xin = x_in + (size_t)b * 5184;
    for (int idx = t; idx < 5184; idx += NT) {
        int i = idx >> 6, d = idx & 63;
        xs[i * 66 + d] = xin[idx];
    }
    __syncthreads();

    layer_fn<81, 9, 0, false>(xs, ybf, qbf, kbf, vT, ws, b_qkv, b_o,
                              ln1_g, ln1_b, ln2_g, ln2_b, b1, b2, out, b, t);
    layer_fn<49, 7, 1, false>(xs, ybf, qbf, kbf, vT, ws, b_qkv, b_o,
                              ln1_g, ln1_b, ln2_g, ln2_b, b1, b2, out, b, t);
    layer_fn<25, 5, 2, false>(xs, ybf, qbf, kbf, vT, ws, b_qkv, b_o,
                              ln1_g, ln1_b, ln2_g, ln2_b, b1, b2, out, b, t);
    layer_fn<9, 3, 3, true>(xs, ybf, qbf, kbf, vT, ws, b_qkv, b_o,
                            ln1_g, ln1_b, ln2_g, ln2_b, b1, b2, out, b, t);
}

extern "C" void kernel_launch(void* const* d_in, const int* in_sizes, int n_in,
                              void* d_out, int out_size, void* d_ws, size_t ws_size,
                              hipStream_t stream) {
    (void)n_in; (void)out_size; (void)ws_size;
    const float* x     = (const float*)d_in[0];
    const float* w_qkv = (const float*)d_in[1];
    const float* b_qkv = (const float*)d_in[2];
    const float* w_o   = (const float*)d_in[3];
    const float* b_o   = (const float*)d_in[4];
    const float* ln1_g = (const float*)d_in[5];
    const float* ln1_b = (const float*)d_in[6];
    const float* ln2_g = (const float*)d_in[7];
    const float* ln2_b = (const float*)d_in[8];
    const float* w1    = (const float*)d_in[9];
    const float* b1    = (const float*)d_in[10];
    const float* w2    = (const float*)d_in[11];
    const float* b2    = (const float*)d_in[12];
    short* ws = (short*)d_ws;

    prep_kernel<<<dim3((WS_TOT + 255) / 256), dim3(256), 0, stream>>>(w_qkv, w_o, w1, w2, ws);

    int B = in_sizes[0] / (81 * 64);
    vit_kernel<<<dim3(B), dim3(NT), 0, stream>>>(
        x, ws, b_qkv, b_o, ln1_g, ln1_b, ln2_g, ln2_b, b1, b2, (float*)d_out);
}

// Round 6
// 407.636 us; speedup vs baseline: 5.7522x; 1.3541x over previous
//
#include <hip/hip_runtime.h>
#include <math.h>

#define NT 512

typedef __attribute__((ext_vector_type(8))) short short8v;
typedef __attribute__((ext_vector_type(4))) short short4v;
typedef __attribute__((ext_vector_type(4))) float f32x4;
typedef __attribute__((ext_vector_type(2))) unsigned uint2v;
typedef __attribute__((ext_vector_type(4))) unsigned uint4v;

__device__ __forceinline__ unsigned short f2bf(float x) {
    unsigned u = __float_as_uint(x);
    unsigned r = ((u >> 16) & 1u) + 0x7FFFu;
    return (unsigned short)((u + r) >> 16);
}
__device__ __forceinline__ unsigned pack2bf(float a, float b) {
    return (unsigned)f2bf(a) | ((unsigned)f2bf(b) << 16);
}
// tanh-form gelu via exp2 + rcp (|err| vs erf-gelu ~3e-3, inside tolerance)
__device__ __forceinline__ float gelu_f(float x) {
    float x3 = x * x * x;
    float e = exp2f(-2.3022079f * x - 0.1029432f * x3);
    return x / (1.0f + e);
}
__device__ __forceinline__ f32x4 mfma32(short8v a, short8v b, f32x4 c) {
    return __builtin_amdgcn_mfma_f32_16x16x32_bf16(a, b, c, 0, 0, 0);
}

// ws layout (bf16 shorts): wqkvT[L][192][64] @0 ; woT[L][64][64] @49152 ;
//                          w1T[L][16][64] @65536 (rows j>=8 zero) ; w2T[L][64][8] @69632
#define WS_WO 49152
#define WS_W1 65536
#define WS_W2 69632
#define WS_TOT 71680

__global__ __launch_bounds__(256) void prep_kernel(
    const float* __restrict__ w_qkv, const float* __restrict__ w_o,
    const float* __restrict__ w1, const float* __restrict__ w2,
    short* __restrict__ ws)
{
    int idx = blockIdx.x * 256 + threadIdx.x;
    if (idx < WS_WO) {
        int l = idx / 12288, r = idx % 12288, c = r >> 6, d = r & 63;
        ws[idx] = (short)f2bf(w_qkv[l * 12288 + d * 192 + c]);
    } else if (idx < WS_W1) {
        int k = idx - WS_WO; int l = k / 4096, r = k % 4096, c = r >> 6, d = r & 63;
        ws[idx] = (short)f2bf(w_o[l * 4096 + d * 64 + c]);
    } else if (idx < WS_W2) {
        int k = idx - WS_W1; int l = k / 1024, r = k % 1024, j = r >> 6, d = r & 63;
        ws[idx] = (j < 8) ? (short)f2bf(w1[l * 512 + d * 8 + j]) : (short)0;
    } else if (idx < WS_TOT) {
        int k = idx - WS_W2; int l = k / 512, r = k % 512, c = r >> 3, j = r & 7;
        ws[idx] = (short)f2bf(w2[l * 512 + j * 64 + c]);
    }
}

// LDS: xs fp32 [81][68] (full 9x9 grid, never cropped; layer L maps token (r,c)
//      to grid row (r+L)*9 + c+L); ybf/qbf/kbf bf16 [96][72]; vT bf16 [64][104].
// hb (MLP hidden, [96][8]) aliases qbf (dead after attention).
template<int N, int P, int L, bool LAST>
__device__ __forceinline__ void layer_fn(
    float* __restrict__ xs, short* __restrict__ ybf, short* __restrict__ qbf,
    short* __restrict__ kbf, short* __restrict__ vT,
    const short* __restrict__ ws,
    const float* __restrict__ b_qkv, const float* __restrict__ b_o,
    const float* __restrict__ ln1_g, const float* __restrict__ ln1_b,
    const float* __restrict__ ln2_g, const float* __restrict__ ln2_b,
    const float* __restrict__ b1,    const float* __restrict__ b2,
    float* __restrict__ out, int b, int t)
{
    constexpr int Mt = (N + 15) / 16;
    constexpr float SC = 0.35355339059327373f;
    const int wv = t >> 6, l = t & 63, lr = l & 15, lq = l >> 4;
    short8v zero8 = {};
    f32x4 zero4 = {0.f, 0.f, 0.f, 0.f};

    // ---- phase 1: LN1 -> ybf. 4 lanes per token (quad stays branch-uniform) ----
    if (t < 64 * Mt) {
        const int token = t >> 2, part = t & 3, d0 = part * 16;
        short* yrow = ybf + token * 72 + d0;
        if (token < N) {
            const int row = (token / P + L) * 9 + token % P + L;
            const float* xr = xs + row * 68 + d0;
            f32x4 v[4];
            #pragma unroll
            for (int k = 0; k < 4; ++k) v[k] = *(const f32x4*)(xr + 4 * k);
            float s1 = 0.f, s2 = 0.f;
            #pragma unroll
            for (int k = 0; k < 4; ++k)
                #pragma unroll
                for (int e = 0; e < 4; ++e) { s1 += v[k][e]; s2 += v[k][e] * v[k][e]; }
            s1 += __shfl_xor(s1, 1); s2 += __shfl_xor(s2, 1);
            s1 += __shfl_xor(s1, 2); s2 += __shfl_xor(s2, 2);
            const float m = s1 * 0.015625f;
            const float r = rsqrtf(s2 * 0.015625f - m * m + 1e-5f);
            uint4v w0, w1v;
            #pragma unroll
            for (int k = 0; k < 4; ++k) {
                f32x4 g  = *(const f32x4*)&ln1_g[L * 64 + d0 + 4 * k];
                f32x4 bb = *(const f32x4*)&ln1_b[L * 64 + d0 + 4 * k];
                unsigned p0 = pack2bf((v[k][0]-m)*r*g[0]+bb[0], (v[k][1]-m)*r*g[1]+bb[1]);
                unsigned p1 = pack2bf((v[k][2]-m)*r*g[2]+bb[2], (v[k][3]-m)*r*g[3]+bb[3]);
                if (k == 0) { w0.x = p0; w0.y = p1; }
                else if (k == 1) { w0.z = p0; w0.w = p1; }
                else if (k == 2) { w1v.x = p0; w1v.y = p1; }
                else { w1v.z = p0; w1v.w = p1; }
            }
            *(uint4v*)yrow = w0;
            *(uint4v*)(yrow + 8) = w1v;
        } else {
            uint4v z = {};
            *(uint4v*)yrow = z;
            *(uint4v*)(yrow + 8) = z;
        }
    }
    __syncthreads();

    // ---- phase 2: qkv GEMM (round-4 verbatim: A=tokens, B=weights) ----
    {
        const short* wqL = ws + L * 12288;
        for (int u = wv; u < Mt * 12; u += 8) {
            int mt = u / 12, ct = u - mt * 12;
            const short* ar = &ybf[(16 * mt + lr) * 72 + lq * 8];
            short8v a0 = *(const short8v*)ar;
            short8v a1 = *(const short8v*)(ar + 32);
            const short* br = &wqL[(16 * ct + lr) * 64 + lq * 8];
            short8v b0 = *(const short8v*)br;
            short8v b1v = *(const short8v*)(br + 32);
            f32x4 acc = mfma32(a0, b0, zero4);
            acc = mfma32(a1, b1v, acc);
            int c = 16 * ct + lr;
            float bias = b_qkv[L * 192 + c];
            if (ct < 4) {
                #pragma unroll
                for (int rg = 0; rg < 4; ++rg)
                    qbf[(16 * mt + lq * 4 + rg) * 72 + c] = (short)f2bf(acc[rg] + bias);
            } else if (ct < 8) {
                #pragma unroll
                for (int rg = 0; rg < 4; ++rg)
                    kbf[(16 * mt + lq * 4 + rg) * 72 + (c - 64)] = (short)f2bf(acc[rg] + bias);
            } else {
                #pragma unroll
                for (int rg = 0; rg < 4; ++rg) {
                    int i = 16 * mt + lq * 4 + rg;
                    if (i < N) vT[(c - 128) * 104 + i] = (short)f2bf(acc[rg] + bias);
                }
            }
        }
    }
    __syncthreads();

    // ---- phase 3: attention. wave = head; K/V fragments hoisted (loop-invariant);
    //      round-4 numerics: __expf(S*SC), mask all tiles, normalize before pack ----
    {
        const int h = wv, hh = wv >> 1;
        short8v kf[Mt];
        #pragma unroll
        for (int jt = 0; jt < Mt; ++jt)
            kf[jt] = (l < 16) ? *(const short8v*)&kbf[(16 * jt + lr) * 72 + h * 8] : zero8;
#if __has_builtin(__builtin_amdgcn_mfma_f32_16x16x16bf16_1k)
        short4v vf[Mt];
        #pragma unroll
        for (int jt = 0; jt < Mt; ++jt)
            vf[jt] = *(const short4v*)&vT[(16 * hh + lr) * 104 + 16 * jt + lq * 4];
#else
        constexpr int KS2 = (Mt + 1) / 2;
        short8v vf8[KS2];
        #pragma unroll
        for (int ks = 0; ks < KS2; ++ks)
            vf8[ks] = *(const short8v*)&vT[(16 * hh + lr) * 104 + 32 * ks + lq * 8];
#endif
        for (int mt = 0; mt < Mt; ++mt) {
            short8v bq = (l < 16) ? *(const short8v*)&qbf[(16 * mt + lr) * 72 + h * 8] : zero8;
            f32x4 acc[Mt];
            #pragma unroll
            for (int jt = 0; jt < Mt; ++jt) acc[jt] = mfma32(kf[jt], bq, zero4);
            float psum = 0.f;
            #pragma unroll
            for (int jt = 0; jt < Mt; ++jt) {
                #pragma unroll
                for (int rg = 0; rg < 4; ++rg) {
                    const int j = 16 * jt + lq * 4 + rg;
                    float e = __expf(acc[jt][rg] * SC);
                    e = (j < N) ? e : 0.f;
                    acc[jt][rg] = e;
                    psum += e;
                }
            }
            float den = psum + __shfl_xor(psum, 16);
            den += __shfl_xor(den, 32);
            const float dinv = 1.0f / den;
            unsigned pkk[Mt][2];
            #pragma unroll
            for (int jt = 0; jt < Mt; ++jt) {
                pkk[jt][0] = pack2bf(acc[jt][0] * dinv, acc[jt][1] * dinv);
                pkk[jt][1] = pack2bf(acc[jt][2] * dinv, acc[jt][3] * dinv);
            }
            f32x4 po = zero4;
#if __has_builtin(__builtin_amdgcn_mfma_f32_16x16x16bf16_1k)
            #pragma unroll
            for (int jt = 0; jt < Mt; ++jt) {
                uint2v pw; pw.x = pkk[jt][0]; pw.y = pkk[jt][1];
                short4v bv = __builtin_bit_cast(short4v, pw);
                po = __builtin_amdgcn_mfma_f32_16x16x16bf16_1k(vf[jt], bv, po, 0, 0, 0);
            }
#else
            #pragma unroll
            for (int ks = 0; ks < KS2; ++ks) {
                const int t1ok = (2 * ks + 1) < Mt;
                unsigned pA0 = pkk[2 * ks][0], pA1 = pkk[2 * ks][1];
                unsigned pB0 = t1ok ? pkk[2 * ks + 1][0] : 0u;
                unsigned pB1 = t1ok ? pkk[2 * ks + 1][1] : 0u;
                int i01 = ((((lq & 1) * 2) * 16) + lr) * 4;
                int i23 = ((((lq & 1) * 2 + 1) * 16) + lr) * 4;
                unsigned w0a = (unsigned)__builtin_amdgcn_ds_bpermute(i01, (int)pA0);
                unsigned w0b = (unsigned)__builtin_amdgcn_ds_bpermute(i01, (int)pB0);
                unsigned w1a = (unsigned)__builtin_amdgcn_ds_bpermute(i01, (int)pA1);
                unsigned w1b = (unsigned)__builtin_amdgcn_ds_bpermute(i01, (int)pB1);
                unsigned w2a = (unsigned)__builtin_amdgcn_ds_bpermute(i23, (int)pA0);
                unsigned w2b = (unsigned)__builtin_amdgcn_ds_bpermute(i23, (int)pB0);
                unsigned w3a = (unsigned)__builtin_amdgcn_ds_bpermute(i23, (int)pA1);
                unsigned w3b = (unsigned)__builtin_amdgcn_ds_bpermute(i23, (int)pB1);
                uint4v wv4;
                wv4.x = (lq >> 1) ? w0b : w0a;
                wv4.y = (lq >> 1) ? w1b : w1a;
                wv4.z = (lq >> 1) ? w2b : w2a;
                wv4.w = (lq >> 1) ? w3b : w3a;
                short8v bv = __builtin_bit_cast(short8v, wv4);
                po = mfma32(vf8[ks], bv, po);
            }
#endif
            if ((lq >> 1) == (h & 1)) {
                const int i = 16 * mt + lr;
                if (i < N) {
                    #pragma unroll
                    for (int rg = 0; rg < 4; ++rg)
                        ybf[i * 72 + h * 8 + (lq & 1) * 4 + rg] = (short)f2bf(po[rg]);
                }
            }
        }
    }
    __syncthreads();

    // ---- phase 4: w_o GEMM + residual into xs (ring write) ----
    {
        const short* woL = ws + WS_WO + L * 4096;
        for (int u = wv; u < Mt * 4; u += 8) {
            int mt = u >> 2, ct = u & 3;
            const short* ar = &ybf[(16 * mt + lr) * 72 + lq * 8];
            short8v a0 = *(const short8v*)ar;
            short8v a1 = *(const short8v*)(ar + 32);
            const short* br = &woL[(16 * ct + lr) * 64 + lq * 8];
            short8v b0 = *(const short8v*)br;
            short8v b1v = *(const short8v*)(br + 32);
            f32x4 acc = mfma32(a0, b0, zero4);
            acc = mfma32(a1, b1v, acc);
            int c = 16 * ct + lr;
            float bias = b_o[L * 64 + c];
            #pragma unroll
            for (int rg = 0; rg < 4; ++rg) {
                int i = 16 * mt + lq * 4 + rg;
                if (i < N) {
                    const int row = (i / P + L) * 9 + i % P + L;
                    xs[row * 68 + c] += acc[rg] + bias;
                }
            }
        }
    }
    __syncthreads();

    // ---- phase 5: LN2 -> ybf (same vectorized form as LN1) ----
    if (t < 64 * Mt) {
        const int token = t >> 2, part = t & 3, d0 = part * 16;
        short* yrow = ybf + token * 72 + d0;
        if (token < N) {
            const int row = (token / P + L) * 9 + token % P + L;
            const float* xr = xs + row * 68 + d0;
            f32x4 v[4];
            #pragma unroll
            for (int k = 0; k < 4; ++k) v[k] = *(const f32x4*)(xr + 4 * k);
            float s1 = 0.f, s2 = 0.f;
            #pragma unroll
            for (int k = 0; k < 4; ++k)
                #pragma unroll
                for (int e = 0; e < 4; ++e) { s1 += v[k][e]; s2 += v[k][e] * v[k][e]; }
            s1 += __shfl_xor(s1, 1); s2 += __shfl_xor(s2, 1);
            s1 += __shfl_xor(s1, 2); s2 += __shfl_xor(s2, 2);
            const float m = s1 * 0.015625f;
            const float r = rsqrtf(s2 * 0.015625f - m * m + 1e-5f);
            uint4v w0, w1v;
            #pragma unroll
            for (int k = 0; k < 4; ++k) {
                f32x4 g  = *(const f32x4*)&ln2_g[L * 64 + d0 + 4 * k];
                f32x4 bb = *(const f32x4*)&ln2_b[L * 64 + d0 + 4 * k];
                unsigned p0 = pack2bf((v[k][0]-m)*r*g[0]+bb[0], (v[k][1]-m)*r*g[1]+bb[1]);
                unsigned p1 = pack2bf((v[k][2]-m)*r*g[2]+bb[2], (v[k][3]-m)*r*g[3]+bb[3]);
                if (k == 0) { w0.x = p0; w0.y = p1; }
                else if (k == 1) { w0.z = p0; w0.w = p1; }
                else if (k == 2) { w1v.x = p0; w1v.y = p1; }
                else { w1v.z = p0; w1v.w = p1; }
            }
            *(uint4v*)yrow = w0;
            *(uint4v*)(yrow + 8) = w1v;
        } else {
            uint4v z = {};
            *(uint4v*)yrow = z;
            *(uint4v*)(yrow + 8) = z;
        }
    }
    __syncthreads();

    // ---- phase 6: MLP up: hb = gelu(ybf @ w1 + b1) ----
    short* hb = qbf;  // qbf dead after attention
    {
        const short* w1L = ws + WS_W1 + L * 1024;
        for (int u = wv; u < Mt; u += 8) {
            const short* ar = &ybf[(16 * u + lr) * 72 + lq * 8];
            short8v a0 = *(const short8v*)ar;
            short8v a1 = *(const short8v*)(ar + 32);
            const short* br = &w1L[lr * 64 + lq * 8];
            short8v b0 = *(const short8v*)br;
            short8v b1v = *(const short8v*)(br + 32);
            f32x4 acc = mfma32(a0, b0, zero4);
            acc = mfma32(a1, b1v, acc);
            if (lr < 8) {
                float bg = b1[L * 8 + lr];
                #pragma unroll
                for (int rg = 0; rg < 4; ++rg)
                    hb[(16 * u + lq * 4 + rg) * 8 + lr] = (short)f2bf(gelu_f(acc[rg] + bg));
            }
        }
    }
    __syncthreads();

    // ---- phase 7: MLP down + residual (K=8, ring write) ----
    {
        const short* w2L = ws + WS_W2 + L * 512;
        for (int u = wv; u < Mt * 4; u += 8) {
            int mt = u >> 2, ct = u & 3;
            short8v a = zero8, bb = zero8;
            if (l < 16) {
                a  = *(const short8v*)&hb[(16 * mt + lr) * 8];
                bb = *(const short8v*)&w2L[(16 * ct + lr) * 8];
            }
            f32x4 acc = mfma32(a, bb, zero4);
            int c = 16 * ct + lr;
            float bias = b2[L * 64 + c];
            #pragma unroll
            for (int rg = 0; rg < 4; ++rg) {
                int i = 16 * mt + lq * 4 + rg;
                if (i < N) {
                    const int row = (i / P + L) * 9 + i % P + L;
                    xs[row * 68 + c] += acc[rg] + bias;
                }
            }
        }
    }
    __syncthreads();

    if (LAST) {
        for (int idx = t; idx < 576; idx += NT) {
            const int d = idx / 9, rc = idx % 9;
            const int row = (rc / 3 + 3) * 9 + rc % 3 + 3;
            out[(size_t)b * 576 + idx] = xs[row * 68 + d];
        }
    }
}

__global__ __launch_bounds__(NT, 4) void vit_kernel(
    const float* __restrict__ x_in, const short* __restrict__ ws,
    const float* __restrict__ b_qkv, const float* __restrict__ b_o,
    const float* __restrict__ ln1_g, const float* __restrict__ ln1_b,
    const float* __restrict__ ln2_g, const float* __restrict__ ln2_b,
    const float* __restrict__ b1,    const float* __restrict__ b2,
    float* __restrict__ out)
{
    __shared__ __align__(16) float xs[81 * 68];
    __shared__ __align__(16) short ybf[96 * 72];
    __shared__ __align__(16) short qbf[96 * 72];
    __shared__ __align__(16) short kbf[96 * 72];
    __shared__ __align__(16) short vT[64 * 104];

    const int b = blockIdx.x;
    const int t = threadIdx.x;

    // zero vT once: pad cols are hit by PV with P=0, and 0*NaN = NaN in MFMA
    for (int idx = t; idx < 64 * 104; idx += NT) vT[idx] = 0;

    const float* xin = x_in + (size_t)b * 5184;
    for (int q4 = t; q4 < 1296; q4 += NT) {
        const int i = q4 >> 4, dq = q4 & 15;
        *(f32x4*)&xs[i * 68 + dq * 4] = *(const f32x4*)&xin[i * 64 + dq * 4];
    }
    __syncthreads();

    layer_fn<81, 9, 0, false>(xs, ybf, qbf, kbf, vT, ws, b_qkv, b_o,
                              ln1_g, ln1_b, ln2_g, ln2_b, b1, b2, out, b, t);
    layer_fn<49, 7, 1, false>(xs, ybf, qbf, kbf, vT, ws, b_qkv, b_o,
                              ln1_g, ln1_b, ln2_g, ln2_b, b1, b2, out, b, t);
    layer_fn<25, 5, 2, false>(xs, ybf, qbf, kbf, vT, ws, b_qkv, b_o,
                              ln1_g, ln1_b, ln2_g, ln2_b, b1, b2, out, b, t);
    layer_fn<9, 3, 3, true>(xs, ybf, qbf, kbf, vT, ws, b_qkv, b_o,
                            ln1_g, ln1_b, ln2_g, ln2_b, b1, b2, out, b, t);
}

extern "C" void kernel_launch(void* const* d_in, const int* in_sizes, int n_in,
                              void* d_out, int out_size, void* d_ws, size_t ws_size,
                              hipStream_t stream) {
    (void)n_in; (void)out_size; (void)ws_size;
    const float* x     = (const float*)d_in[0];
    const float* w_qkv = (const float*)d_in[1];
    const float* b_qkv = (const float*)d_in[2];
    const float* w_o   = (const float*)d_in[3];
    const float* b_o   = (const float*)d_in[4];
    const float* ln1_g = (const float*)d_in[5];
    const float* ln1_b = (const float*)d_in[6];
    const float* ln2_g = (const float*)d_in[7];
    const float* ln2_b = (const float*)d_in[8];
    const float* w1    = (const float*)d_in[9];
    const float* b1    = (const float*)d_in[10];
    const float* w2    = (const float*)d_in[11];
    const float* b2    = (const float*)d_in[12];
    short* ws = (short*)d_ws;

    prep_kernel<<<dim3((WS_TOT + 255) / 256), dim3(256), 0, stream>>>(w_qkv, w_o, w1, w2, ws);

    int B = in_sizes[0] / (81 * 64);
    vit_kernel<<<dim3(B), dim3(NT), 0, stream>>>(
        x, ws, b_qkv, b_o, ln1_g, ln1_b, ln2_g, ln2_b, b1, b2, (float*)d_out);
}

// Round 8
// 398.034 us; speedup vs baseline: 5.8910x; 1.0241x over previous
//
#include <hip/hip_runtime.h>
#include <hip/hip_bf16.h>
#include <math.h>

#define NT 512

typedef __attribute__((ext_vector_type(8))) short short8v;
typedef __attribute__((ext_vector_type(4))) short short4v;
typedef __attribute__((ext_vector_type(4))) float f32x4;
typedef __attribute__((ext_vector_type(2))) unsigned uint2v;
typedef __attribute__((ext_vector_type(4))) unsigned uint4v;

__device__ __forceinline__ unsigned short f2bf(float x) {   // prep kernel only
    unsigned u = __float_as_uint(x);
    unsigned r = ((u >> 16) & 1u) + 0x7FFFu;
    return (unsigned short)((u + r) >> 16);
}
// compiler-sanctioned f32 -> bf16 converts (lowered to HW cvt on gfx950)
__device__ __forceinline__ unsigned pk2(float a, float b) {
    __hip_bfloat162 h = __float22bfloat162_rn(make_float2(a, b));
    unsigned r;
    __builtin_memcpy(&r, &h, sizeof(r));
    return r;
}
__device__ __forceinline__ short bf1(float a) {
    __hip_bfloat16 h = __float2bfloat16(a);
    short r;
    __builtin_memcpy(&r, &h, sizeof(r));
    return r;
}
// tanh-form gelu via exp2 + rcp (|err| vs erf-gelu ~3e-3, inside tolerance)
__device__ __forceinline__ float gelu_f(float x) {
    float x3 = x * x * x;
    float e = exp2f(-2.3022079f * x - 0.1029432f * x3);
    return x / (1.0f + e);
}
__device__ __forceinline__ f32x4 mfma32(short8v a, short8v b, f32x4 c) {
    return __builtin_amdgcn_mfma_f32_16x16x32_bf16(a, b, c, 0, 0, 0);
}

// ws layout (bf16 shorts): wqkvT[L][192][64] @0 ; woT[L][64][64] @49152 ;
//                          w1T[L][16][64] @65536 (rows j>=8 zero) ; w2T[L][64][8] @69632
#define WS_WO 49152
#define WS_W1 65536
#define WS_W2 69632
#define WS_TOT 71680

__global__ __launch_bounds__(256) void prep_kernel(
    const float* __restrict__ w_qkv, const float* __restrict__ w_o,
    const float* __restrict__ w1, const float* __restrict__ w2,
    short* __restrict__ ws)
{
    int idx = blockIdx.x * 256 + threadIdx.x;
    if (idx < WS_WO) {
        int l = idx / 12288, r = idx % 12288, c = r >> 6, d = r & 63;
        ws[idx] = (short)f2bf(w_qkv[l * 12288 + d * 192 + c]);
    } else if (idx < WS_W1) {
        int k = idx - WS_WO; int l = k / 4096, r = k % 4096, c = r >> 6, d = r & 63;
        ws[idx] = (short)f2bf(w_o[l * 4096 + d * 64 + c]);
    } else if (idx < WS_W2) {
        int k = idx - WS_W1; int l = k / 1024, r = k % 1024, j = r >> 6, d = r & 63;
        ws[idx] = (j < 8) ? (short)f2bf(w1[l * 512 + d * 8 + j]) : (short)0;
    } else if (idx < WS_TOT) {
        int k = idx - WS_W2; int l = k / 512, r = k % 512, c = r >> 3, j = r & 7;
        ws[idx] = (short)f2bf(w2[l * 512 + j * 64 + c]);
    }
}

// LDS: xs fp32 [81][68] (full 9x9 grid, never cropped; layer L maps token (r,c)
//      to grid row (r+L)*9 + c+L); ybf/qbf/kbf bf16 [96][72]; vT bf16 [64][104].
// hb (MLP hidden, [96][8]) aliases qbf (dead after attention).
template<int N, int P, int L, bool LAST>
__device__ __forceinline__ void layer_fn(
    float* __restrict__ xs, short* __restrict__ ybf, short* __restrict__ qbf,
    short* __restrict__ kbf, short* __restrict__ vT,
    const short* __restrict__ ws,
    const float* __restrict__ b_qkv, const float* __restrict__ b_o,
    const float* __restrict__ ln1_g, const float* __restrict__ ln1_b,
    const float* __restrict__ ln2_g, const float* __restrict__ ln2_b,
    const float* __restrict__ b1,    const float* __restrict__ b2,
    float* __restrict__ out, int b, int t)
{
    constexpr int Mt = (N + 15) / 16;
    constexpr float SC = 0.35355339059327373f;
    const int wv = t >> 6, l = t & 63, lr = l & 15, lq = l >> 4;
    short8v zero8 = {};
    f32x4 zero4 = {0.f, 0.f, 0.f, 0.f};

    // ---- phase 1: LN1 -> ybf. 4 lanes per token (quad stays branch-uniform) ----
    if (t < 64 * Mt) {
        const int token = t >> 2, part = t & 3, d0 = part * 16;
        short* yrow = ybf + token * 72 + d0;
        if (token < N) {
            const int row = (token / P + L) * 9 + token % P + L;
            const float* xr = xs + row * 68 + d0;
            f32x4 v[4];
            #pragma unroll
            for (int k = 0; k < 4; ++k) v[k] = *(const f32x4*)(xr + 4 * k);
            float s1 = 0.f, s2 = 0.f;
            #pragma unroll
            for (int k = 0; k < 4; ++k)
                #pragma unroll
                for (int e = 0; e < 4; ++e) { s1 += v[k][e]; s2 += v[k][e] * v[k][e]; }
            s1 += __shfl_xor(s1, 1); s2 += __shfl_xor(s2, 1);
            s1 += __shfl_xor(s1, 2); s2 += __shfl_xor(s2, 2);
            const float m = s1 * 0.015625f;
            const float r = rsqrtf(s2 * 0.015625f - m * m + 1e-5f);
            uint4v w0, w1v;
            #pragma unroll
            for (int k = 0; k < 4; ++k) {
                f32x4 g  = *(const f32x4*)&ln1_g[L * 64 + d0 + 4 * k];
                f32x4 bb = *(const f32x4*)&ln1_b[L * 64 + d0 + 4 * k];
                unsigned p0 = pk2((v[k][0]-m)*r*g[0]+bb[0], (v[k][1]-m)*r*g[1]+bb[1]);
                unsigned p1 = pk2((v[k][2]-m)*r*g[2]+bb[2], (v[k][3]-m)*r*g[3]+bb[3]);
                if (k == 0) { w0.x = p0; w0.y = p1; }
                else if (k == 1) { w0.z = p0; w0.w = p1; }
                else if (k == 2) { w1v.x = p0; w1v.y = p1; }
                else { w1v.z = p0; w1v.w = p1; }
            }
            *(uint4v*)yrow = w0;
            *(uint4v*)(yrow + 8) = w1v;
        } else {
            uint4v z = {};
            *(uint4v*)yrow = z;
            *(uint4v*)(yrow + 8) = z;
        }
    }
    __syncthreads();

    // ---- phase 2: qkv GEMM. q/k operand-swapped (C^T: lane=token, 4 consecutive
    //      channels -> packed b32 writes); v unswapped (lane=channel, consecutive
    //      tokens -> packed b32 writes into vT). Softmax scale folded into q. ----
    {
        const short* wqL = ws + L * 12288;
        for (int u = wv; u < Mt * 12; u += 8) {
            const int mt = u / 12, ct = u - mt * 12;
            const short* yr = &ybf[(16 * mt + lr) * 72 + lq * 8];
            short8v y0 = *(const short8v*)yr, y1 = *(const short8v*)(yr + 32);
            const short* wr = &wqL[(16 * ct + lr) * 64 + lq * 8];
            short8v w0 = *(const short8v*)wr, w1 = *(const short8v*)(wr + 32);
            if (ct < 8) {
                f32x4 acc = mfma32(w0, y0, zero4);
                acc = mfma32(w1, y1, acc);
                f32x4 bq = *(const f32x4*)&b_qkv[L * 192 + 16 * ct + lq * 4];
                const int i = 16 * mt + lr;   // token
                if (ct < 4) {   // q: fold softmax scale
                    unsigned p0 = pk2((acc[0]+bq[0])*SC, (acc[1]+bq[1])*SC);
                    unsigned p1 = pk2((acc[2]+bq[2])*SC, (acc[3]+bq[3])*SC);
                    unsigned* dst = (unsigned*)&qbf[i * 72 + 16 * ct + lq * 4];
                    dst[0] = p0; dst[1] = p1;
                } else {
                    unsigned p0 = pk2(acc[0]+bq[0], acc[1]+bq[1]);
                    unsigned p1 = pk2(acc[2]+bq[2], acc[3]+bq[3]);
                    unsigned* dst = (unsigned*)&kbf[i * 72 + 16 * (ct - 4) + lq * 4];
                    dst[0] = p0; dst[1] = p1;
                }
            } else {
                f32x4 acc = mfma32(y0, w0, zero4);
                acc = mfma32(y1, w1, acc);
                const int cv = 16 * (ct - 8) + lr;   // v channel
                const float bias = b_qkv[L * 192 + 128 + cv];
                unsigned p0 = pk2(acc[0]+bias, acc[1]+bias);
                unsigned p1 = pk2(acc[2]+bias, acc[3]+bias);
                unsigned* dst = (unsigned*)&vT[cv * 104 + 16 * mt + lq * 4];
                dst[0] = p0; dst[1] = p1;
            }
        }
    }
    __syncthreads();

    // ---- phase 3: attention. wave = head; K/V fragments hoisted (loop-invariant);
    //      q pre-scaled -> e = expf(S) directly; normalize before pack ----
    {
        const int h = wv, hh = wv >> 1;
        short8v kf[Mt];
        #pragma unroll
        for (int jt = 0; jt < Mt; ++jt)
            kf[jt] = (l < 16) ? *(const short8v*)&kbf[(16 * jt + lr) * 72 + h * 8] : zero8;
#if __has_builtin(__builtin_amdgcn_mfma_f32_16x16x16bf16_1k)
        short4v vf[Mt];
        #pragma unroll
        for (int jt = 0; jt < Mt; ++jt)
            vf[jt] = *(const short4v*)&vT[(16 * hh + lr) * 104 + 16 * jt + lq * 4];
#else
        constexpr int KS2 = (Mt + 1) / 2;
        short8v vf8[KS2];
        #pragma unroll
        for (int ks = 0; ks < KS2; ++ks)
            vf8[ks] = *(const short8v*)&vT[(16 * hh + lr) * 104 + 32 * ks + lq * 8];
#endif
        for (int mt = 0; mt < Mt; ++mt) {
            short8v bq = (l < 16) ? *(const short8v*)&qbf[(16 * mt + lr) * 72 + h * 8] : zero8;
            f32x4 acc[Mt];
            #pragma unroll
            for (int jt = 0; jt < Mt; ++jt) acc[jt] = mfma32(kf[jt], bq, zero4);
            float psum = 0.f;
            #pragma unroll
            for (int jt = 0; jt < Mt; ++jt) {
                #pragma unroll
                for (int rg = 0; rg < 4; ++rg) {
                    const int j = 16 * jt + lq * 4 + rg;
                    float e = __expf(acc[jt][rg]);
                    e = (j < N) ? e : 0.f;
                    acc[jt][rg] = e;
                    psum += e;
                }
            }
            float den = psum + __shfl_xor(psum, 16);
            den += __shfl_xor(den, 32);
            const float dinv = 1.0f / den;
            unsigned pkk[Mt][2];
            #pragma unroll
            for (int jt = 0; jt < Mt; ++jt) {
                pkk[jt][0] = pk2(acc[jt][0] * dinv, acc[jt][1] * dinv);
                pkk[jt][1] = pk2(acc[jt][2] * dinv, acc[jt][3] * dinv);
            }
            f32x4 po = zero4;
#if __has_builtin(__builtin_amdgcn_mfma_f32_16x16x16bf16_1k)
            #pragma unroll
            for (int jt = 0; jt < Mt; ++jt) {
                uint2v pw; pw.x = pkk[jt][0]; pw.y = pkk[jt][1];
                short4v bv = __builtin_bit_cast(short4v, pw);
                po = __builtin_amdgcn_mfma_f32_16x16x16bf16_1k(vf[jt], bv, po, 0, 0, 0);
            }
#else
            #pragma unroll
            for (int ks = 0; ks < KS2; ++ks) {
                const int t1ok = (2 * ks + 1) < Mt;
                unsigned pA0 = pkk[2 * ks][0], pA1 = pkk[2 * ks][1];
                unsigned pB0 = t1ok ? pkk[2 * ks + 1][0] : 0u;
                unsigned pB1 = t1ok ? pkk[2 * ks + 1][1] : 0u;
                int i01 = ((((lq & 1) * 2) * 16) + lr) * 4;
                int i23 = ((((lq & 1) * 2 + 1) * 16) + lr) * 4;
                unsigned w0a = (unsigned)__builtin_amdgcn_ds_bpermute(i01, (int)pA0);
                unsigned w0b = (unsigned)__builtin_amdgcn_ds_bpermute(i01, (int)pB0);
                unsigned w1a = (unsigned)__builtin_amdgcn_ds_bpermute(i01, (int)pA1);
                unsigned w1b = (unsigned)__builtin_amdgcn_ds_bpermute(i01, (int)pB1);
                unsigned w2a = (unsigned)__builtin_amdgcn_ds_bpermute(i23, (int)pA0);
                unsigned w2b = (unsigned)__builtin_amdgcn_ds_bpermute(i23, (int)pB0);
                unsigned w3a = (unsigned)__builtin_amdgcn_ds_bpermute(i23, (int)pA1);
                unsigned w3b = (unsigned)__builtin_amdgcn_ds_bpermute(i23, (int)pB1);
                uint4v wv4;
                wv4.x = (lq >> 1) ? w0b : w0a;
                wv4.y = (lq >> 1) ? w1b : w1a;
                wv4.z = (lq >> 1) ? w2b : w2a;
                wv4.w = (lq >> 1) ? w3b : w3a;
                short8v bv = __builtin_bit_cast(short8v, wv4);
                po = mfma32(vf8[ks], bv, po);
            }
#endif
            if ((lq >> 1) == (h & 1)) {
                const int i = 16 * mt + lr;
                if (i < N) {
                    unsigned q0 = pk2(po[0], po[1]);
                    unsigned q1 = pk2(po[2], po[3]);
                    unsigned* dst = (unsigned*)&ybf[i * 72 + h * 8 + (lq & 1) * 4];
                    dst[0] = q0; dst[1] = q1;
                }
            }
        }
    }
    __syncthreads();

    // ---- phase 4: w_o GEMM + residual into xs (ring write) ----
    {
        const short* woL = ws + WS_WO + L * 4096;
        for (int u = wv; u < Mt * 4; u += 8) {
            int mt = u >> 2, ct = u & 3;
            const short* ar = &ybf[(16 * mt + lr) * 72 + lq * 8];
            short8v a0 = *(const short8v*)ar;
            short8v a1 = *(const short8v*)(ar + 32);
            const short* br = &woL[(16 * ct + lr) * 64 + lq * 8];
            short8v b0 = *(const short8v*)br;
            short8v b1v = *(const short8v*)(br + 32);
            f32x4 acc = mfma32(a0, b0, zero4);
            acc = mfma32(a1, b1v, acc);
            int c = 16 * ct + lr;
            float bias = b_o[L * 64 + c];
            #pragma unroll
            for (int rg = 0; rg < 4; ++rg) {
                int i = 16 * mt + lq * 4 + rg;
                if (i < N) {
                    const int row = (i / P + L) * 9 + i % P + L;
                    xs[row * 68 + c] += acc[rg] + bias;
                }
            }
        }
    }
    __syncthreads();

    // ---- phase 5: LN2 -> ybf (same vectorized form as LN1) ----
    if (t < 64 * Mt) {
        const int token = t >> 2, part = t & 3, d0 = part * 16;
        short* yrow = ybf + token * 72 + d0;
        if (token < N) {
            const int row = (token / P + L) * 9 + token % P + L;
            const float* xr = xs + row * 68 + d0;
            f32x4 v[4];
            #pragma unroll
            for (int k = 0; k < 4; ++k) v[k] = *(const f32x4*)(xr + 4 * k);
            float s1 = 0.f, s2 = 0.f;
            #pragma unroll
            for (int k = 0; k < 4; ++k)
                #pragma unroll
                for (int e = 0; e < 4; ++e) { s1 += v[k][e]; s2 += v[k][e] * v[k][e]; }
            s1 += __shfl_xor(s1, 1); s2 += __shfl_xor(s2, 1);
            s1 += __shfl_xor(s1, 2); s2 += __shfl_xor(s2, 2);
            const float m = s1 * 0.015625f;
            const float r = rsqrtf(s2 * 0.015625f - m * m + 1e-5f);
            uint4v w0, w1v;
            #pragma unroll
            for (int k = 0; k < 4; ++k) {
                f32x4 g  = *(const f32x4*)&ln2_g[L * 64 + d0 + 4 * k];
                f32x4 bb = *(const f32x4*)&ln2_b[L * 64 + d0 + 4 * k];
                unsigned p0 = pk2((v[k][0]-m)*r*g[0]+bb[0], (v[k][1]-m)*r*g[1]+bb[1]);
                unsigned p1 = pk2((v[k][2]-m)*r*g[2]+bb[2], (v[k][3]-m)*r*g[3]+bb[3]);
                if (k == 0) { w0.x = p0; w0.y = p1; }
                else if (k == 1) { w0.z = p0; w0.w = p1; }
                else if (k == 2) { w1v.x = p0; w1v.y = p1; }
                else { w1v.z = p0; w1v.w = p1; }
            }
            *(uint4v*)yrow = w0;
            *(uint4v*)(yrow + 8) = w1v;
        } else {
            uint4v z = {};
            *(uint4v*)yrow = z;
            *(uint4v*)(yrow + 8) = z;
        }
    }
    __syncthreads();

    // ---- phase 6: MLP up: hb = gelu(ybf @ w1 + b1) ----
    short* hb = qbf;  // qbf dead after attention
    {
        const short* w1L = ws + WS_W1 + L * 1024;
        for (int u = wv; u < Mt; u += 8) {
            const short* ar = &ybf[(16 * u + lr) * 72 + lq * 8];
            short8v a0 = *(const short8v*)ar;
            short8v a1 = *(const short8v*)(ar + 32);
            const short* br = &w1L[lr * 64 + lq * 8];
            short8v b0 = *(const short8v*)br;
            short8v b1v = *(const short8v*)(br + 32);
            f32x4 acc = mfma32(a0, b0, zero4);
            acc = mfma32(a1, b1v, acc);
            if (lr < 8) {
                float bg = b1[L * 8 + lr];
                #pragma unroll
                for (int rg = 0; rg < 4; ++rg)
                    hb[(16 * u + lq * 4 + rg) * 8 + lr] = bf1(gelu_f(acc[rg] + bg));
            }
        }
    }
    __syncthreads();

    // ---- phase 7: MLP down + residual (K=8, ring write) ----
    {
        const short* w2L = ws + WS_W2 + L * 512;
        for (int u = wv; u < Mt * 4; u += 8) {
            int mt = u >> 2, ct = u & 3;
            short8v a = zero8, bb = zero8;
            if (l < 16) {
                a  = *(const short8v*)&hb[(16 * mt + lr) * 8];
                bb = *(const short8v*)&w2L[(16 * ct + lr) * 8];
            }
            f32x4 acc = mfma32(a, bb, zero4);
            int c = 16 * ct + lr;
            float bias = b2[L * 64 + c];
            #pragma unroll
            for (int rg = 0; rg < 4; ++rg) {
                int i = 16 * mt + lq * 4 + rg;
                if (i < N) {
                    const int row = (i / P + L) * 9 + i % P + L;
                    xs[row * 68 + c] += acc[rg] + bias;
                }
            }
        }
    }
    __syncthreads();

    if (LAST) {
        for (int idx = t; idx < 576; idx += NT) {
            const int d = idx / 9, rc = idx % 9;
            const int row = (rc / 3 + 3) * 9 + rc % 3 + 3;
            out[(size_t)b * 576 + idx] = xs[row * 68 + d];
        }
    }
}

__global__ __launch_bounds__(NT, 4) void vit_kernel(
    const float* __restrict__ x_in, const short* __restrict__ ws,
    const float* __restrict__ b_qkv, const float* __restrict__ b_o,
    const float* __restrict__ ln1_g, const float* __restrict__ ln1_b,
    const float* __restrict__ ln2_g, const float* __restrict__ ln2_b,
    const float* __restrict__ b1,    const float* __restrict__ b2,
    float* __restrict__ out)
{
    __shared__ __align__(16) float xs[81 * 68];
    __shared__ __align__(16) short ybf[96 * 72];
    __shared__ __align__(16) short qbf[96 * 72];
    __shared__ __align__(16) short kbf[96 * 72];
    __shared__ __align__(16) short vT[64 * 104];

    const int b = blockIdx.x;
    const int t = threadIdx.x;

    // zero vT once: pad cols are hit by PV with P=0, and 0*NaN = NaN in MFMA
    for (int idx = t; idx < 64 * 104; idx += NT) vT[idx] = 0;

    const float* xin = x_in + (size_t)b * 5184;
    for (int q4 = t; q4 < 1296; q4 += NT) {
        const int i = q4 >> 4, dq = q4 & 15;
        *(f32x4*)&xs[i * 68 + dq * 4] = *(const f32x4*)&xin[i * 64 + dq * 4];
    }
    __syncthreads();

    layer_fn<81, 9, 0, false>(xs, ybf, qbf, kbf, vT, ws, b_qkv, b_o,
                              ln1_g, ln1_b, ln2_g, ln2_b, b1, b2, out, b, t);
    layer_fn<49, 7, 1, false>(xs, ybf, qbf, kbf, vT, ws, b_qkv, b_o,
                              ln1_g, ln1_b, ln2_g, ln2_b, b1, b2, out, b, t);
    layer_fn<25, 5, 2, false>(xs, ybf, qbf, kbf, vT, ws, b_qkv, b_o,
                              ln1_g, ln1_b, ln2_g, ln2_b, b1, b2, out, b, t);
    layer_fn<9, 3, 3, true>(xs, ybf, qbf, kbf, vT, ws, b_qkv, b_o,
                            ln1_g, ln1_b, ln2_g, ln2_b, b1, b2, out, b, t);
}

extern "C" void kernel_launch(void* const* d_in, const int* in_sizes, int n_in,
                              void* d_out, int out_size, void* d_ws, size_t ws_size,
                              hipStream_t stream) {
    (void)n_in; (void)out_size; (void)ws_size;
    const float* x     = (const float*)d_in[0];
    const float* w_qkv = (const float*)d_in[1];
    const float* b_qkv = (const float*)d_in[2];
    const float* w_o   = (const float*)d_in[3];
    const float* b_o   = (const float*)d_in[4];
    const float* ln1_g = (const float*)d_in[5];
    const float* ln1_b = (const float*)d_in[6];
    const float* ln2_g = (const float*)d_in[7];
    const float* ln2_b = (const float*)d_in[8];
    const float* w1    = (const float*)d_in[9];
    const float* b1    = (const float*)d_in[10];
    const float* w2    = (const float*)d_in[11];
    const float* b2    = (const float*)d_in[12];
    short* ws = (short*)d_ws;

    prep_kernel<<<dim3((WS_TOT + 255) / 256), dim3(256), 0, stream>>>(w_qkv, w_o, w1, w2, ws);

    int B = in_sizes[0] / (81 * 64);
    vit_kernel<<<dim3(B), dim3(NT), 0, stream>>>(
        x, ws, b_qkv, b_o, ln1_g, ln1_b, ln2_g, ln2_b, b1, b2, (float*)d_out);
}